// Round 5
// baseline (818.337 us; speedup 1.0000x reference)
//
#include <hip/hip_runtime.h>
#include <stdint.h>

#define N_V   16384
#define M_E   8192
#define CIN   128
#define COUT  64
#define RCAP  128   // per-vertex edge-list capacity (Poisson(41): overflow ~1e-13)
#define CCAP  192   // per-edge vertex-list capacity (Poisson(82): overflow ~1e-18)
#define BCAP  16    // per-lane bucket slots (Binomial(128,.005): P(>16) ~ 1e-20)
#define SCAP4 256   // staged (e,n) pairs per 4-row WG (mean 164, +7 sigma)
#define NWG1  (N_V / 4)   // 4096 streaming WGs
#define NBAND 256         // 64-row bands
#define WPB   16          // streaming WGs per band

// DIAGNOSTIC BUILD: k_rows / k_edge / k_vertex run their (idempotent) body
// TWICE so each doubled dispatch crosses the ~345us poison-fill bar and
// becomes visible in the rocprof top-5 with its counters. dur_us delta vs
// round 3 (755.9) = K1 + K3 + K4 exactly.

// workspace layout (bytes), all offsets 16B-aligned
#define OFF_ROWCNT  0
#define OFF_COLCNT  (OFF_ROWCNT + N_V * 4)            // 64 KB
#define OFF_ROWLIST (OFF_COLCNT + M_E * 4)            // +32 KB
#define OFF_COLLIST (OFF_ROWLIST + N_V * RCAP * 2)    // +4 MB
#define OFF_PART    (OFF_COLLIST + M_E * CCAP * 2)    // +3 MB
#define OFF_OFFT    (OFF_PART + NBAND * M_E * 2)      // +4 MB
#define OFF_STAGED  (OFF_OFFT + NBAND * M_E * 2)      // +4 MB
#define OFF_STGCNT  (OFF_STAGED + NWG1 * SCAP4 * 4)   // +4 MB
#define OFF_YV      (OFF_STGCNT + NWG1 * 4)           // +16 KB
#define OFF_E       (OFF_YV + N_V * COUT * 4)         // +4 MB

// ---------------------------------------------------------------------------
// K1a: stream H once per rep, one wave per row. Body identical to the
// round-3 passing version; rep-doubled for self-profiling.
// ---------------------------------------------------------------------------
__global__ __launch_bounds__(256) void k_rows(
    const uint4* __restrict__ H4,
    int* __restrict__ row_cnt, unsigned short* __restrict__ row_list,
    unsigned int* __restrict__ staged, int* __restrict__ staged_cnt) {
  __shared__ unsigned short bucket[4][BCAP + 1][64];
  __shared__ unsigned int ls_stage[SCAP4];
  __shared__ int ls_n;
  int wid  = threadIdx.x >> 6;
  int lane = threadIdx.x & 63;
  int n    = blockIdx.x * 4 + wid;                 // gridDim.x = N_V/4
  const uint4* rp = H4 + (size_t)n * (M_E / 4) + lane;
  unsigned short (*bk)[64] = bucket[wid];
#pragma unroll 1
  for (int rep = 0; rep < 2; ++rep) {
    if (threadIdx.x == 0) ls_n = 0;
    __syncthreads();
    int cnt = 0;
    int mb  = lane * 4;                            // this lane's column base
#pragma unroll 8
    for (int it = 0; it < (M_E / 4) / 64; ++it) {  // 32 iterations
      uint4 v = rp[it * 64];
      // H entries are 0.0f / 1.0f: nonzero bits <=> nonzero float
      int w;
      w = cnt > BCAP ? BCAP : cnt; bk[w][lane] = (unsigned short)(mb + 0); cnt += (v.x != 0u);
      w = cnt > BCAP ? BCAP : cnt; bk[w][lane] = (unsigned short)(mb + 1); cnt += (v.y != 0u);
      w = cnt > BCAP ? BCAP : cnt; bk[w][lane] = (unsigned short)(mb + 2); cnt += (v.z != 0u);
      w = cnt > BCAP ? BCAP : cnt; bk[w][lane] = (unsigned short)(mb + 3); cnt += (v.w != 0u);
      mb += 256;
    }
    if (cnt > BCAP) cnt = BCAP;
    // inclusive prefix sum of per-lane counts across the wave (6 shfl steps)
    int pfx = cnt;
#pragma unroll
    for (int s = 1; s < 64; s <<= 1) {
      int t = __shfl_up(pfx, s, 64);
      if (lane >= s) pfx += t;
    }
    int total = __shfl(pfx, 63, 64);
    int start = pfx - cnt;
    unsigned short* rl = row_list + n * RCAP;
    for (int k = 0; k < cnt; ++k) {                // max ~4 iterations
      int p = start + k;
      int e = bk[k][lane];
      if (p < RCAP) rl[p] = (unsigned short)e;
      int sp = atomicAdd(&ls_n, 1);                // LDS atomic, cheap
      if (sp < SCAP4) ls_stage[sp] = ((unsigned int)e << 6) | (unsigned int)(n & 63);
    }
    if (lane == 63) row_cnt[n] = total > RCAP ? RCAP : total;
    __syncthreads();
    int sn = ls_n; if (sn > SCAP4) sn = SCAP4;
    for (int j = threadIdx.x; j < sn; j += 256)
      staged[blockIdx.x * SCAP4 + j] = ls_stage[j];
    if (threadIdx.x == 0) staged_cnt[blockIdx.x] = sn;
    __syncthreads();
    asm volatile("" ::: "memory");                 // keep rep 1 materialized
  }
}

// ---------------------------------------------------------------------------
// K1b: per-band edge histogram from the staged lists (LDS atomics only).
// ---------------------------------------------------------------------------
__global__ __launch_bounds__(256) void k_hist(
    const unsigned int* __restrict__ staged, const int* __restrict__ staged_cnt,
    unsigned short* __restrict__ partial) {
  __shared__ unsigned int hist[M_E];   // 32 KB
  for (int j = threadIdx.x; j < M_E; j += 256) hist[j] = 0;
  __syncthreads();
  int b = blockIdx.x;                  // gridDim.x = NBAND
  for (int w = 0; w < WPB; ++w) {
    int wg = b * WPB + w;
    int c  = staged_cnt[wg];
    for (int j = threadIdx.x; j < c; j += 256)
      atomicAdd(&hist[staged[wg * SCAP4 + j] >> 6], 1u);
  }
  __syncthreads();
  for (int j = threadIdx.x; j < M_E; j += 256)
    partial[b * M_E + j] = (unsigned short)hist[j];
}

// ---------------------------------------------------------------------------
// K1c: per-edge exclusive prefix across the 256 bands -> off[band][e].
// ---------------------------------------------------------------------------
__global__ __launch_bounds__(64) void k_prefix(
    const unsigned short* __restrict__ partial,
    unsigned short* __restrict__ offt, int* __restrict__ col_cnt) {
  int e = blockIdx.x * 64 + threadIdx.x;   // gridDim.x = M_E/64 = 128
  int run = 0;
#pragma unroll 8
  for (int b = 0; b < NBAND; ++b) {
    int v = partial[b * M_E + e];
    offt[b * M_E + e] = (unsigned short)run;
    run += v;
  }
  col_cnt[e] = run;
}

// ---------------------------------------------------------------------------
// K1d: deterministic col_list scatter (LDS offset counters; bands disjoint).
// ---------------------------------------------------------------------------
__global__ __launch_bounds__(256) void k_scatter(
    const unsigned int* __restrict__ staged, const int* __restrict__ staged_cnt,
    const unsigned short* __restrict__ offt,
    unsigned short* __restrict__ col_list) {
  __shared__ unsigned int off_l[M_E];  // 32 KB
  int b = blockIdx.x;                  // gridDim.x = NBAND
  for (int j = threadIdx.x; j < M_E; j += 256) off_l[j] = offt[b * M_E + j];
  __syncthreads();
  for (int w = 0; w < WPB; ++w) {
    int wg = b * WPB + w;
    int c  = staged_cnt[wg];
    for (int j = threadIdx.x; j < c; j += 256) {
      unsigned int s = staged[wg * SCAP4 + j];
      int e  = (int)(s >> 6);
      int nl = (int)(s & 63u);
      int slot = (int)atomicAdd(&off_l[e], 1u);    // LDS atomic
      if (slot < CCAP) col_list[e * CCAP + slot] = (unsigned short)(b * 64 + nl);
    }
  }
}

// ---------------------------------------------------------------------------
// K2: Yv[n,c] = dv[n] * (X[n,:] . W[c,:] + b[c])
// ---------------------------------------------------------------------------
__global__ __launch_bounds__(256) void k_project(
    const float* __restrict__ X, const float* __restrict__ W,
    const float* __restrict__ b, const int* __restrict__ row_cnt,
    float* __restrict__ Yv) {
  int wid  = threadIdx.x >> 6;
  int lane = threadIdx.x & 63;
  int cb   = __builtin_amdgcn_readfirstlane(wid);
  int n    = blockIdx.x * 64 + lane;                // gridDim.x = 256
  const float* xrow  = X + n * CIN;
  const float* wbase = W + cb * 16 * CIN;

  float acc[16];
#pragma unroll
  for (int j = 0; j < 16; ++j) acc[j] = 0.f;

  for (int k4 = 0; k4 < CIN / 4; ++k4) {
    float4 x = *(const float4*)(xrow + k4 * 4);
#pragma unroll
    for (int j = 0; j < 16; ++j) {
      float4 w = *(const float4*)(wbase + j * CIN + k4 * 4);
      acc[j] += x.x * w.x + x.y * w.y + x.z * w.z + x.w * w.w;
    }
  }

  int cnt  = row_cnt[n];
  float dv = cnt > 0 ? rsqrtf((float)cnt) : 0.f;
  float* yrow = Yv + n * COUT + cb * 16;
#pragma unroll
  for (int g = 0; g < 4; ++g) {
    float4 o;
    o.x = dv * (acc[4 * g + 0] + b[cb * 16 + 4 * g + 0]);
    o.y = dv * (acc[4 * g + 1] + b[cb * 16 + 4 * g + 1]);
    o.z = dv * (acc[4 * g + 2] + b[cb * 16 + 4 * g + 2]);
    o.w = dv * (acc[4 * g + 3] + b[cb * 16 + 4 * g + 3]);
    *(float4*)(yrow + 4 * g) = o;
  }
}

// ---------------------------------------------------------------------------
// K3: E[m,:] = (1/de_cnt[m]) * sum_{n in col_list[m]} Yv[n,:]  (rep-doubled)
// ---------------------------------------------------------------------------
__global__ __launch_bounds__(256) void k_edge(
    const float* __restrict__ Yv, const int* __restrict__ col_cnt,
    const unsigned short* __restrict__ col_list, float* __restrict__ E) {
  int wid  = threadIdx.x >> 6;
  int lane = threadIdx.x & 63;
  int m    = blockIdx.x * 4 + wid;      // gridDim.x = M_E/4
  int realcnt = col_cnt[m];
  int cnt  = realcnt > CCAP ? CCAP : realcnt;
  const unsigned short* lst = col_list + m * CCAP;
#pragma unroll 1
  for (int rep = 0; rep < 2; ++rep) {
    float acc = 0.f;
    int i = 0;
    for (; i + 8 <= cnt; i += 8) {
      uint4 u = *(const uint4*)(lst + i);
      int n0 = u.x & 0xffff, n1 = u.x >> 16;
      int n2 = u.y & 0xffff, n3 = u.y >> 16;
      int n4 = u.z & 0xffff, n5 = u.z >> 16;
      int n6 = u.w & 0xffff, n7 = u.w >> 16;
      float a0 = Yv[n0 * COUT + lane];
      float a1 = Yv[n1 * COUT + lane];
      float a2 = Yv[n2 * COUT + lane];
      float a3 = Yv[n3 * COUT + lane];
      float a4 = Yv[n4 * COUT + lane];
      float a5 = Yv[n5 * COUT + lane];
      float a6 = Yv[n6 * COUT + lane];
      float a7 = Yv[n7 * COUT + lane];
      acc += ((a0 + a1) + (a2 + a3)) + ((a4 + a5) + (a6 + a7));
    }
    for (; i < cnt; ++i) acc += Yv[(int)lst[i] * COUT + lane];
    float den = realcnt > 0 ? 1.f / (float)realcnt : 0.f;
    E[m * COUT + lane] = den * acc;
    asm volatile("" ::: "memory");                 // keep rep 1 materialized
  }
}

// ---------------------------------------------------------------------------
// K4: out[n,:] = relu(dv[n] * sum_{m in row_list[n]} E[m,:])   (rep-doubled)
// ---------------------------------------------------------------------------
__global__ __launch_bounds__(256) void k_vertex(
    const float* __restrict__ E, const int* __restrict__ row_cnt,
    const unsigned short* __restrict__ row_list, float* __restrict__ out) {
  int wid  = threadIdx.x >> 6;
  int lane = threadIdx.x & 63;
  int n    = blockIdx.x * 4 + wid;      // gridDim.x = N_V/4
  int cnt  = row_cnt[n];
  const unsigned short* lst = row_list + n * RCAP;
#pragma unroll 1
  for (int rep = 0; rep < 2; ++rep) {
    float acc = 0.f;
    int i = 0;
    for (; i + 8 <= cnt; i += 8) {
      uint4 u = *(const uint4*)(lst + i);
      int m0 = u.x & 0xffff, m1 = u.x >> 16;
      int m2 = u.y & 0xffff, m3 = u.y >> 16;
      int m4 = u.z & 0xffff, m5 = u.z >> 16;
      int m6 = u.w & 0xffff, m7 = u.w >> 16;
      float a0 = E[m0 * COUT + lane];
      float a1 = E[m1 * COUT + lane];
      float a2 = E[m2 * COUT + lane];
      float a3 = E[m3 * COUT + lane];
      float a4 = E[m4 * COUT + lane];
      float a5 = E[m5 * COUT + lane];
      float a6 = E[m6 * COUT + lane];
      float a7 = E[m7 * COUT + lane];
      acc += ((a0 + a1) + (a2 + a3)) + ((a4 + a5) + (a6 + a7));
    }
    for (; i < cnt; ++i) acc += E[(int)lst[i] * COUT + lane];
    float dv = cnt > 0 ? rsqrtf((float)cnt) : 0.f;
    out[n * COUT + lane] = fmaxf(dv * acc, 0.f);
    asm volatile("" ::: "memory");                 // keep rep 1 materialized
  }
}

// ---------------------------------------------------------------------------
extern "C" void kernel_launch(void* const* d_in, const int* in_sizes, int n_in,
                              void* d_out, int out_size, void* d_ws, size_t ws_size,
                              hipStream_t stream) {
  const float* X = (const float*)d_in[0];   // (N_V, CIN)
  const float* H = (const float*)d_in[1];   // (N_V, M_E)
  const float* W = (const float*)d_in[2];   // (COUT, CIN)
  const float* b = (const float*)d_in[3];   // (COUT,)
  float* out = (float*)d_out;               // (N_V, COUT) fp32

  char* ws = (char*)d_ws;
  int* row_cnt = (int*)(ws + OFF_ROWCNT);
  int* col_cnt = (int*)(ws + OFF_COLCNT);
  unsigned short* row_list = (unsigned short*)(ws + OFF_ROWLIST);
  unsigned short* col_list = (unsigned short*)(ws + OFF_COLLIST);
  unsigned short* partial  = (unsigned short*)(ws + OFF_PART);
  unsigned short* offt     = (unsigned short*)(ws + OFF_OFFT);
  unsigned int*   staged   = (unsigned int*)(ws + OFF_STAGED);
  int*            stg_cnt  = (int*)(ws + OFF_STGCNT);
  float* Yv = (float*)(ws + OFF_YV);
  float* E  = (float*)(ws + OFF_E);

  k_rows<<<NWG1, 256, 0, stream>>>((const uint4*)H, row_cnt, row_list,
                                   staged, stg_cnt);
  k_hist<<<NBAND, 256, 0, stream>>>(staged, stg_cnt, partial);
  k_prefix<<<M_E / 64, 64, 0, stream>>>(partial, offt, col_cnt);
  k_scatter<<<NBAND, 256, 0, stream>>>(staged, stg_cnt, offt, col_list);
  k_project<<<N_V / 64, 256, 0, stream>>>(X, W, b, row_cnt, Yv);
  k_edge<<<M_E / 4, 256, 0, stream>>>(Yv, col_cnt, col_list, E);
  k_vertex<<<N_V / 4, 256, 0, stream>>>(E, row_cnt, row_list, out);
}

// Round 8
// 736.386 us; speedup vs baseline: 1.1113x; 1.1113x over previous
//
#include <hip/hip_runtime.h>
#include <stdint.h>

#define N_V   16384
#define M_E   8192
#define CIN   128
#define COUT  64
#define RCAP  128   // per-vertex edge-list capacity (Poisson(41): overflow ~1e-13)
#define CCAP  192   // per-edge vertex-list capacity (Poisson(82): overflow ~1e-18)
#define BCAP  16    // per-lane bucket slots (Binomial(128,.005): P(>16) ~ 1e-20)
#define CSTRIDE 16  // col_cnt padded: one counter per 64B cache line

// workspace layout (bytes), all offsets 16B-aligned
#define OFF_ROWCNT  0
#define OFF_COLCNT  (N_V * 4)                         // 65536
#define OFF_ROWLIST (OFF_COLCNT + M_E * CSTRIDE * 4)  // + 512 KB
#define OFF_COLLIST (OFF_ROWLIST + N_V * RCAP * 2)    // + 4 MB
#define OFF_YV      (OFF_COLLIST + M_E * CCAP * 2)    // + 3 MB
#define OFF_E       (OFF_YV + N_V * COUT * 4)         // + 4 MB

// ---------------------------------------------------------------------------
// K1: stream H once, one wave per row (proven round-2 body; HBM-bound ~90us).
// ---------------------------------------------------------------------------
__global__ __launch_bounds__(256) void k_rows(
    const uint4* __restrict__ H4,
    int* __restrict__ row_cnt, unsigned short* __restrict__ row_list,
    int* __restrict__ col_cnt, unsigned short* __restrict__ col_list) {
  __shared__ unsigned short bucket[4][BCAP + 1][64];
  int wid  = threadIdx.x >> 6;
  int lane = threadIdx.x & 63;
  int n    = blockIdx.x * 4 + wid;                 // gridDim.x = N_V/4
  const uint4* rp = H4 + (size_t)n * (M_E / 4) + lane;
  unsigned short (*bk)[64] = bucket[wid];
  int cnt = 0;
  int mb  = lane * 4;                              // this lane's column base
#pragma unroll 8
  for (int it = 0; it < (M_E / 4) / 64; ++it) {    // 32 iterations
    uint4 v = rp[it * 64];
    // H entries are 0.0f / 1.0f: nonzero bits <=> nonzero float
    int w;
    w = cnt > BCAP ? BCAP : cnt; bk[w][lane] = (unsigned short)(mb + 0); cnt += (v.x != 0u);
    w = cnt > BCAP ? BCAP : cnt; bk[w][lane] = (unsigned short)(mb + 1); cnt += (v.y != 0u);
    w = cnt > BCAP ? BCAP : cnt; bk[w][lane] = (unsigned short)(mb + 2); cnt += (v.z != 0u);
    w = cnt > BCAP ? BCAP : cnt; bk[w][lane] = (unsigned short)(mb + 3); cnt += (v.w != 0u);
    mb += 256;
  }
  if (cnt > BCAP) cnt = BCAP;
  // inclusive prefix sum of per-lane counts across the wave (6 shfl steps)
  int pfx = cnt;
#pragma unroll
  for (int s = 1; s < 64; s <<= 1) {
    int t = __shfl_up(pfx, s, 64);
    if (lane >= s) pfx += t;
  }
  int total = __shfl(pfx, 63, 64);
  int start = pfx - cnt;
  unsigned short* rl = row_list + n * RCAP;
  for (int k = 0; k < cnt; ++k) {                  // max ~4 iterations
    int p = start + k;
    int e = bk[k][lane];
    if (p < RCAP) rl[p] = (unsigned short)e;
    int cp = atomicAdd(&col_cnt[e * CSTRIDE], 1);
    if (cp < CCAP) col_list[e * CCAP + cp] = (unsigned short)n;
  }
  if (lane == 63) row_cnt[n] = total > RCAP ? RCAP : total;
}

// ---------------------------------------------------------------------------
// K2: Yv[n,c] = dv[n] * (X[n,:] . W[c,:] + b[c])
// ---------------------------------------------------------------------------
__global__ __launch_bounds__(256) void k_project(
    const float* __restrict__ X, const float* __restrict__ W,
    const float* __restrict__ b, const int* __restrict__ row_cnt,
    float* __restrict__ Yv) {
  int wid  = threadIdx.x >> 6;
  int lane = threadIdx.x & 63;
  int cb   = __builtin_amdgcn_readfirstlane(wid);
  int n    = blockIdx.x * 64 + lane;                // gridDim.x = 256
  const float* xrow  = X + n * CIN;
  const float* wbase = W + cb * 16 * CIN;

  float acc[16];
#pragma unroll
  for (int j = 0; j < 16; ++j) acc[j] = 0.f;

  for (int k4 = 0; k4 < CIN / 4; ++k4) {
    float4 x = *(const float4*)(xrow + k4 * 4);
#pragma unroll
    for (int j = 0; j < 16; ++j) {
      float4 w = *(const float4*)(wbase + j * CIN + k4 * 4);
      acc[j] += x.x * w.x + x.y * w.y + x.z * w.z + x.w * w.w;
    }
  }

  int cnt  = row_cnt[n];
  float dv = cnt > 0 ? rsqrtf((float)cnt) : 0.f;
  float* yrow = Yv + n * COUT + cb * 16;
#pragma unroll
  for (int g = 0; g < 4; ++g) {
    float4 o;
    o.x = dv * (acc[4 * g + 0] + b[cb * 16 + 4 * g + 0]);
    o.y = dv * (acc[4 * g + 1] + b[cb * 16 + 4 * g + 1]);
    o.z = dv * (acc[4 * g + 2] + b[cb * 16 + 4 * g + 2]);
    o.w = dv * (acc[4 * g + 3] + b[cb * 16 + 4 * g + 3]);
    *(float4*)(yrow + 4 * g) = o;
  }
}

// ---------------------------------------------------------------------------
// K3: E[m,:] = (1/de_cnt[m]) * sum_{n in col_list[m]} Yv[n,:]
// Latency-bound on L3/cross-XCD gathers (each = 4 cache lines): 16 gathers
// in flight per wave (was 8) to double MLP toward the per-CU miss-buffer cap.
// ---------------------------------------------------------------------------
__global__ __launch_bounds__(256) void k_edge(
    const float* __restrict__ Yv, const int* __restrict__ col_cnt,
    const unsigned short* __restrict__ col_list, float* __restrict__ E) {
  int wid  = threadIdx.x >> 6;
  int lane = threadIdx.x & 63;
  int m    = blockIdx.x * 4 + wid;      // gridDim.x = M_E/4
  int realcnt = col_cnt[m * CSTRIDE];
  int cnt  = realcnt > CCAP ? CCAP : realcnt;
  const unsigned short* lst = col_list + m * CCAP;
  float acc = 0.f;
  int i = 0;
  for (; i + 16 <= cnt; i += 16) {
    uint4 u0 = *(const uint4*)(lst + i);
    uint4 u1 = *(const uint4*)(lst + i + 8);
    float a0 = Yv[(u0.x & 0xffff) * COUT + lane];
    float a1 = Yv[(u0.x >> 16)   * COUT + lane];
    float a2 = Yv[(u0.y & 0xffff) * COUT + lane];
    float a3 = Yv[(u0.y >> 16)   * COUT + lane];
    float a4 = Yv[(u0.z & 0xffff) * COUT + lane];
    float a5 = Yv[(u0.z >> 16)   * COUT + lane];
    float a6 = Yv[(u0.w & 0xffff) * COUT + lane];
    float a7 = Yv[(u0.w >> 16)   * COUT + lane];
    float a8 = Yv[(u1.x & 0xffff) * COUT + lane];
    float a9 = Yv[(u1.x >> 16)   * COUT + lane];
    float aa = Yv[(u1.y & 0xffff) * COUT + lane];
    float ab = Yv[(u1.y >> 16)   * COUT + lane];
    float ac = Yv[(u1.z & 0xffff) * COUT + lane];
    float ad = Yv[(u1.z >> 16)   * COUT + lane];
    float ae = Yv[(u1.w & 0xffff) * COUT + lane];
    float af = Yv[(u1.w >> 16)   * COUT + lane];
    acc += (((a0 + a1) + (a2 + a3)) + ((a4 + a5) + (a6 + a7))) +
           (((a8 + a9) + (aa + ab)) + ((ac + ad) + (ae + af)));
  }
  for (; i + 8 <= cnt; i += 8) {
    uint4 u = *(const uint4*)(lst + i);
    float a0 = Yv[(u.x & 0xffff) * COUT + lane];
    float a1 = Yv[(u.x >> 16)   * COUT + lane];
    float a2 = Yv[(u.y & 0xffff) * COUT + lane];
    float a3 = Yv[(u.y >> 16)   * COUT + lane];
    float a4 = Yv[(u.z & 0xffff) * COUT + lane];
    float a5 = Yv[(u.z >> 16)   * COUT + lane];
    float a6 = Yv[(u.w & 0xffff) * COUT + lane];
    float a7 = Yv[(u.w >> 16)   * COUT + lane];
    acc += ((a0 + a1) + (a2 + a3)) + ((a4 + a5) + (a6 + a7));
  }
  for (; i < cnt; ++i) acc += Yv[(int)lst[i] * COUT + lane];
  float den = realcnt > 0 ? 1.f / (float)realcnt : 0.f;
  E[m * COUT + lane] = den * acc;
}

// ---------------------------------------------------------------------------
// K4: out[n,:] = relu(dv[n] * sum_{m in row_list[n]} E[m,:])  (16-deep MLP)
// ---------------------------------------------------------------------------
__global__ __launch_bounds__(256) void k_vertex(
    const float* __restrict__ E, const int* __restrict__ row_cnt,
    const unsigned short* __restrict__ row_list, float* __restrict__ out) {
  int wid  = threadIdx.x >> 6;
  int lane = threadIdx.x & 63;
  int n    = blockIdx.x * 4 + wid;      // gridDim.x = N_V/4
  int cnt  = row_cnt[n];
  const unsigned short* lst = row_list + n * RCAP;
  float acc = 0.f;
  int i = 0;
  for (; i + 16 <= cnt; i += 16) {
    uint4 u0 = *(const uint4*)(lst + i);
    uint4 u1 = *(const uint4*)(lst + i + 8);
    float a0 = E[(u0.x & 0xffff) * COUT + lane];
    float a1 = E[(u0.x >> 16)   * COUT + lane];
    float a2 = E[(u0.y & 0xffff) * COUT + lane];
    float a3 = E[(u0.y >> 16)   * COUT + lane];
    float a4 = E[(u0.z & 0xffff) * COUT + lane];
    float a5 = E[(u0.z >> 16)   * COUT + lane];
    float a6 = E[(u0.w & 0xffff) * COUT + lane];
    float a7 = E[(u0.w >> 16)   * COUT + lane];
    float a8 = E[(u1.x & 0xffff) * COUT + lane];
    float a9 = E[(u1.x >> 16)   * COUT + lane];
    float aa = E[(u1.y & 0xffff) * COUT + lane];
    float ab = E[(u1.y >> 16)   * COUT + lane];
    float ac = E[(u1.z & 0xffff) * COUT + lane];
    float ad = E[(u1.z >> 16)   * COUT + lane];
    float ae = E[(u1.w & 0xffff) * COUT + lane];
    float af = E[(u1.w >> 16)   * COUT + lane];
    acc += (((a0 + a1) + (a2 + a3)) + ((a4 + a5) + (a6 + a7))) +
           (((a8 + a9) + (aa + ab)) + ((ac + ad) + (ae + af)));
  }
  for (; i + 8 <= cnt; i += 8) {
    uint4 u = *(const uint4*)(lst + i);
    float a0 = E[(u.x & 0xffff) * COUT + lane];
    float a1 = E[(u.x >> 16)   * COUT + lane];
    float a2 = E[(u.y & 0xffff) * COUT + lane];
    float a3 = E[(u.y >> 16)   * COUT + lane];
    float a4 = E[(u.z & 0xffff) * COUT + lane];
    float a5 = E[(u.z >> 16)   * COUT + lane];
    float a6 = E[(u.w & 0xffff) * COUT + lane];
    float a7 = E[(u.w >> 16)   * COUT + lane];
    acc += ((a0 + a1) + (a2 + a3)) + ((a4 + a5) + (a6 + a7));
  }
  for (; i < cnt; ++i) acc += E[(int)lst[i] * COUT + lane];
  float dv = cnt > 0 ? rsqrtf((float)cnt) : 0.f;
  out[n * COUT + lane] = fmaxf(dv * acc, 0.f);
}

// ---------------------------------------------------------------------------
extern "C" void kernel_launch(void* const* d_in, const int* in_sizes, int n_in,
                              void* d_out, int out_size, void* d_ws, size_t ws_size,
                              hipStream_t stream) {
  const float* X = (const float*)d_in[0];   // (N_V, CIN)
  const float* H = (const float*)d_in[1];   // (N_V, M_E)
  const float* W = (const float*)d_in[2];   // (COUT, CIN)
  const float* b = (const float*)d_in[3];   // (COUT,)
  float* out = (float*)d_out;               // (N_V, COUT) fp32

  char* ws = (char*)d_ws;
  int* row_cnt = (int*)(ws + OFF_ROWCNT);
  int* col_cnt = (int*)(ws + OFF_COLCNT);
  unsigned short* row_list = (unsigned short*)(ws + OFF_ROWLIST);
  unsigned short* col_list = (unsigned short*)(ws + OFF_COLLIST);
  float* Yv = (float*)(ws + OFF_YV);
  float* E  = (float*)(ws + OFF_E);

  // col_cnt must start at zero (ws poisoned each call); 512 KB, ~2 us
  hipMemsetAsync(col_cnt, 0, M_E * CSTRIDE * 4, stream);

  k_rows<<<N_V / 4, 256, 0, stream>>>((const uint4*)H, row_cnt, row_list,
                                      col_cnt, col_list);
  k_project<<<N_V / 64, 256, 0, stream>>>(X, W, b, row_cnt, Yv);
  k_edge<<<M_E / 4, 256, 0, stream>>>(Yv, col_cnt, col_list, E);
  k_vertex<<<N_V / 4, 256, 0, stream>>>(E, row_cnt, row_list, out);
}